// Round 3
// baseline (118.431 us; speedup 1.0000x reference)
//
#include <hip/hip_runtime.h>

#define EMB 128
#define KN 16
#define NREL 32

// ---------------- costab: |cos(rela[r], rela[c])| for all 32x32 pairs -------
__global__ __launch_bounds__(256) void pgra_costab_k(const float* __restrict__ rela,
                                                     float* __restrict__ costab) {
    const int pair = blockIdx.x * 4 + (threadIdx.x >> 6);
    const int lane = threadIdx.x & 63;
    const int r = pair >> 5, c = pair & 31;
    const float2 av = ((const float2*)(rela + (size_t)r * EMB))[lane];
    const float2 bv = ((const float2*)(rela + (size_t)c * EMB))[lane];
    float dot = av.x * bv.x + av.y * bv.y;
    float na  = av.x * av.x + av.y * av.y;
    float nb  = bv.x * bv.x + bv.y * bv.y;
    #pragma unroll
    for (int off = 32; off > 0; off >>= 1) {
        dot += __shfl_xor(dot, off);
        na  += __shfl_xor(na,  off);
        nb  += __shfl_xor(nb,  off);
    }
    if (lane == 0)
        costab[pair] = fabsf(dot / (sqrtf(na) * sqrtf(nb) + 1e-8f));
}

// ---------------- Fused: gather + aggregate + W0 + hop-2 attn + W1 ----------
// One block (16 waves) per batch element b; wave j owns first-hop neighbor j.
// 2 blocks/CU co-resident: one block's tail compute hides under the other's
// gather memory latency.
__global__ __launch_bounds__(1024, 8) void pgra_fused(
    const int* __restrict__ node, const int* __restrict__ relation,
    const int* __restrict__ adj_node, const int* __restrict__ adj_rela,
    const float* __restrict__ node_table, const float* __restrict__ proj_table,
    const float* __restrict__ W0, const float* __restrict__ b0,
    const float* __restrict__ W1, const float* __restrict__ b1,
    const float* __restrict__ costab, float* __restrict__ out)
{
    const int b    = blockIdx.x;
    const int tid  = threadIdx.x;     // 0..1023
    const int wave = tid >> 6;        // 0..15 == first-hop neighbor j
    const int lane = tid & 63;

    __shared__ float s_agg[KN][EMB];  // proj-multiplied hop-1 aggregates
    __shared__ float s_part[2][EMB];  // partial att-weighted tanh sums
    __shared__ float s_fin[EMB];

    const int n0  = node[b];
    const int rel = relation[b];

    // ---- Phase 1: wave j gathers+aggregates its 16 second-hop neighbors ----
    {
        const int j  = wave;
        const int n1 = adj_node[n0 * KN + j];
        const int4* n2p = (const int4*)(adj_node + (size_t)n1 * KN);
        const int4* r1p = (const int4*)(adj_rela + (size_t)n1 * KN);
        int   n2[KN];
        float sc[KN];
        #pragma unroll
        for (int q = 0; q < 4; ++q) {
            const int4 nn = n2p[q];
            const int4 rr = r1p[q];
            n2[4*q+0] = nn.x; n2[4*q+1] = nn.y; n2[4*q+2] = nn.z; n2[4*q+3] = nn.w;
            sc[4*q+0] = costab[rr.x * NREL + rel];
            sc[4*q+1] = costab[rr.y * NREL + rel];
            sc[4*q+2] = costab[rr.z * NREL + rel];
            sc[4*q+3] = costab[rr.w * NREL + rel];
        }
        float m = sc[0];
        #pragma unroll
        for (int k = 1; k < KN; ++k) m = fmaxf(m, sc[k]);
        float sum = 0.f;
        #pragma unroll
        for (int k = 0; k < KN; ++k) { sc[k] = __expf(sc[k] - m); sum += sc[k]; }
        const float inv = 1.f / sum;

        float ax = 0.f, ay = 0.f;
        #pragma unroll
        for (int k = 0; k < KN; ++k) {
            const float2 v = ((const float2*)(node_table + (size_t)n2[k] * EMB))[lane];
            ax = fmaf(sc[k], v.x, ax);
            ay = fmaf(sc[k], v.y, ay);
        }
        const float2 pj = ((const float2*)(proj_table + (size_t)rel * EMB))[lane];
        s_agg[j][2*lane]   = ax * inv * pj.x;
        s_agg[j][2*lane+1] = ay * inv * pj.y;
    }
    __syncthreads();

    // ---- Phase 2: h1[j] = tanh(agg[j] @ W0 + b0), folded with hop-2 attn ----
    // 256 active threads: e = tid&127, group g = tid>>7 handles j = 8g..8g+7.
    // s_agg reads are wave-uniform -> LDS broadcast (free). W0 read 2x/block.
    if (tid < 256) {
        const int e  = tid & 127;
        const int g  = tid >> 7;
        const int jg = g * 8;
        float acc[8];
        const float bias = b0[e];
        #pragma unroll
        for (int q = 0; q < 8; ++q) acc[q] = bias;
        for (int ee4 = 0; ee4 < EMB / 4; ++ee4) {
            const float w0v = W0[(4 * ee4 + 0) * EMB + e];
            const float w1v = W0[(4 * ee4 + 1) * EMB + e];
            const float w2v = W0[(4 * ee4 + 2) * EMB + e];
            const float w3v = W0[(4 * ee4 + 3) * EMB + e];
            #pragma unroll
            for (int q = 0; q < 8; ++q) {
                const float4 a = *(const float4*)&s_agg[jg + q][4 * ee4];
                acc[q] = fmaf(a.x, w0v, fmaf(a.y, w1v, fmaf(a.z, w2v, fmaf(a.w, w3v, acc[q]))));
            }
        }
        // hop-2 attention weights from r0 (broadcast L1 loads, tiny)
        float sc0[KN];
        float m = -1e30f;
        #pragma unroll
        for (int k = 0; k < KN; ++k) {
            sc0[k] = costab[adj_rela[n0 * KN + k] * NREL + rel];
            m = fmaxf(m, sc0[k]);
        }
        float sum = 0.f;
        #pragma unroll
        for (int k = 0; k < KN; ++k) { sc0[k] = __expf(sc0[k] - m); sum += sc0[k]; }
        const float inv = 1.f / sum;
        float part = 0.f;
        #pragma unroll
        for (int q = 0; q < 8; ++q)
            part = fmaf(sc0[jg + q] * inv, tanhf(acc[q]), part);
        s_part[g][e] = part;
    }
    __syncthreads();

    if (tid < EMB) s_fin[tid] = s_part[0][tid] + s_part[1][tid];
    __syncthreads();

    // ---- Phase 4: out = tanh(fin @ W1 + b1) ----
    if (tid < EMB) {
        float acc = b1[tid];
        for (int ee = 0; ee < EMB; ++ee) acc = fmaf(s_fin[ee], W1[ee * EMB + tid], acc);
        out[(size_t)b * EMB + tid] = tanhf(acc);
    }
}

extern "C" void kernel_launch(void* const* d_in, const int* in_sizes, int n_in,
                              void* d_out, int out_size, void* d_ws, size_t ws_size,
                              hipStream_t stream) {
    const int*   node       = (const int*)d_in[0];
    const int*   relation   = (const int*)d_in[1];
    const int*   adj_node   = (const int*)d_in[2];
    const int*   adj_rela   = (const int*)d_in[3];
    const float* node_table = (const float*)d_in[4];
    const float* rela_table = (const float*)d_in[5];
    const float* proj_table = (const float*)d_in[6];
    const float* W0         = (const float*)d_in[7];
    const float* b0         = (const float*)d_in[8];
    const float* W1         = (const float*)d_in[9];
    const float* b1         = (const float*)d_in[10];
    float* outp   = (float*)d_out;
    float* costab = (float*)d_ws;   // 1024 floats = 4 KB
    const int B = in_sizes[0];

    hipLaunchKernelGGL(pgra_costab_k, dim3(NREL * NREL / 4), dim3(256), 0, stream,
                       rela_table, costab);
    hipLaunchKernelGGL(pgra_fused, dim3(B), dim3(1024), 0, stream,
                       node, relation, adj_node, adj_rela,
                       node_table, proj_table, W0, b0, W1, b1, costab, outp);
}

// Round 4
// 95.201 us; speedup vs baseline: 1.2440x; 1.2440x over previous
//
#include <hip/hip_runtime.h>

#define EMB 128
#define KN 16
#define NREL 32

__device__ __forceinline__ float fast_tanh(float x) {
    // exact identity tanh(x) = 1 - 2/(e^{2x}+1); v_exp-based, ~1e-6 abs err.
    const float z = __expf(2.0f * x);
    return 1.0f - __fdividef(2.0f, z + 1.0f);
}

// ---------------- costab: |cos(rela[r], rela[c])| for all 32x32 pairs -------
__global__ __launch_bounds__(256) void pgra_costab_k(const float* __restrict__ rela,
                                                     float* __restrict__ costab) {
    const int pair = blockIdx.x * 4 + (threadIdx.x >> 6);
    const int lane = threadIdx.x & 63;
    const int r = pair >> 5, c = pair & 31;
    const float2 av = ((const float2*)(rela + (size_t)r * EMB))[lane];
    const float2 bv = ((const float2*)(rela + (size_t)c * EMB))[lane];
    float dot = av.x * bv.x + av.y * bv.y;
    float na  = av.x * av.x + av.y * av.y;
    float nb  = bv.x * bv.x + bv.y * bv.y;
    #pragma unroll
    for (int off = 32; off > 0; off >>= 1) {
        dot += __shfl_xor(dot, off);
        na  += __shfl_xor(na,  off);
        nb  += __shfl_xor(nb,  off);
    }
    if (lane == 0)
        costab[pair] = fabsf(dot / (sqrtf(na) * sqrtf(nb) + 1e-8f));
}

// ---------------- Kernel A: gather+aggregate, TWO (b,j) pairs per wave ------
// launch_bounds(256,4): 128-VGPR budget so ~32 gather loads stay in flight.
__global__ __launch_bounds__(256, 4) void pgra_gather2(
    const int* __restrict__ node, const int* __restrict__ relation,
    const int* __restrict__ adj_node, const int* __restrict__ adj_rela,
    const float* __restrict__ node_table, const float* __restrict__ proj_table,
    const float* __restrict__ costab, float* __restrict__ agg, int half)
{
    const int w = blockIdx.x * 4 + (threadIdx.x >> 6);
    if (w >= half) return;
    const int lane = threadIdx.x & 63;
    const int pA = w, pB = w + half;
    const int bA = pA >> 4, jA = pA & 15;
    const int bB = pB >> 4, jB = pB & 15;

    const int n0A = node[bA], relA = relation[bA];
    const int n0B = node[bB], relB = relation[bB];
    const int n1A = adj_node[n0A * KN + jA];
    const int n1B = adj_node[n0B * KN + jB];

    const int4* nAp = (const int4*)(adj_node + (size_t)n1A * KN);
    const int4* rAp = (const int4*)(adj_rela + (size_t)n1A * KN);
    const int4* nBp = (const int4*)(adj_node + (size_t)n1B * KN);
    const int4* rBp = (const int4*)(adj_rela + (size_t)n1B * KN);

    int   n2A[KN], n2B[KN];
    float sA[KN],  sB[KN];
    #pragma unroll
    for (int q = 0; q < 4; ++q) {
        const int4 na4 = nAp[q], nb4 = nBp[q];
        const int4 ra4 = rAp[q], rb4 = rBp[q];
        n2A[4*q+0] = na4.x; n2A[4*q+1] = na4.y; n2A[4*q+2] = na4.z; n2A[4*q+3] = na4.w;
        n2B[4*q+0] = nb4.x; n2B[4*q+1] = nb4.y; n2B[4*q+2] = nb4.z; n2B[4*q+3] = nb4.w;
        sA[4*q+0] = costab[ra4.x * NREL + relA];
        sA[4*q+1] = costab[ra4.y * NREL + relA];
        sA[4*q+2] = costab[ra4.z * NREL + relA];
        sA[4*q+3] = costab[ra4.w * NREL + relA];
        sB[4*q+0] = costab[rb4.x * NREL + relB];
        sB[4*q+1] = costab[rb4.y * NREL + relB];
        sB[4*q+2] = costab[rb4.z * NREL + relB];
        sB[4*q+3] = costab[rb4.w * NREL + relB];
    }

    float mA = sA[0], mB = sB[0];
    #pragma unroll
    for (int k = 1; k < KN; ++k) { mA = fmaxf(mA, sA[k]); mB = fmaxf(mB, sB[k]); }
    float sumA = 0.f, sumB = 0.f;
    #pragma unroll
    for (int k = 0; k < KN; ++k) {
        sA[k] = __expf(sA[k] - mA); sumA += sA[k];
        sB[k] = __expf(sB[k] - mB); sumB += sB[k];
    }
    const float invA = __fdividef(1.f, sumA);
    const float invB = __fdividef(1.f, sumB);

    float axA = 0.f, ayA = 0.f, axB = 0.f, ayB = 0.f;
    #pragma unroll
    for (int k = 0; k < KN; ++k) {
        const float2 vA = ((const float2*)(node_table + (size_t)n2A[k] * EMB))[lane];
        const float2 vB = ((const float2*)(node_table + (size_t)n2B[k] * EMB))[lane];
        axA = fmaf(sA[k], vA.x, axA);
        ayA = fmaf(sA[k], vA.y, ayA);
        axB = fmaf(sB[k], vB.x, axB);
        ayB = fmaf(sB[k], vB.y, ayB);
    }
    const float2 pjA = ((const float2*)(proj_table + (size_t)relA * EMB))[lane];
    const float2 pjB = ((const float2*)(proj_table + (size_t)relB * EMB))[lane];
    float2 oA, oB;
    oA.x = axA * invA * pjA.x;  oA.y = ayA * invA * pjA.y;
    oB.x = axB * invB * pjB.x;  oB.y = ayB * invB * pjB.y;
    ((float2*)(agg + (size_t)pA * EMB))[lane] = oA;
    ((float2*)(agg + (size_t)pB * EMB))[lane] = oB;
}

// ---------------- Kernel B: W0 + hop-2 attention + W1, 2 b per block --------
// Thread (e, bl) owns ALL 16 j of batch element b=2*blk+bl: W0 is read once
// per b (acc[16] reuse), attention folded in-register, fast_tanh everywhere.
__global__ __launch_bounds__(256) void pgra_tail2(
    const int* __restrict__ node, const int* __restrict__ relation,
    const int* __restrict__ adj_rela, const float* __restrict__ agg,
    const float* __restrict__ W0, const float* __restrict__ b0,
    const float* __restrict__ W1, const float* __restrict__ b1,
    const float* __restrict__ costab, float* __restrict__ out)
{
    const int blk = blockIdx.x;
    const int tid = threadIdx.x;
    const int e   = tid & 127;
    const int bl  = tid >> 7;           // 0 or 1
    const int b   = blk * 2 + bl;

    __shared__ float s_agg[2][KN][EMB];   // 16 KB
    __shared__ float s_fin[2][EMB];

    // coalesced load of both agg tiles: 4096 floats = 1024 float4
    {
        const float4* ap = (const float4*)(agg + (size_t)blk * 2 * KN * EMB);
        float4* sp = (float4*)&s_agg[0][0][0];
        #pragma unroll
        for (int q = 0; q < 4; ++q) sp[tid + 256 * q] = ap[tid + 256 * q];
    }
    __syncthreads();

    const int n0  = node[b];
    const int rel = relation[b];

    // h1[j][e] accumulation for all 16 j of this thread's b
    float acc[KN];
    const float bias = b0[e];
    #pragma unroll
    for (int k = 0; k < KN; ++k) acc[k] = bias;
    for (int ee4 = 0; ee4 < EMB / 4; ++ee4) {
        const float w0v = W0[(4 * ee4 + 0) * EMB + e];
        const float w1v = W0[(4 * ee4 + 1) * EMB + e];
        const float w2v = W0[(4 * ee4 + 2) * EMB + e];
        const float w3v = W0[(4 * ee4 + 3) * EMB + e];
        #pragma unroll
        for (int k = 0; k < KN; ++k) {
            const float4 a = *(const float4*)&s_agg[bl][k][4 * ee4];  // LDS broadcast
            acc[k] = fmaf(a.x, w0v, fmaf(a.y, w1v, fmaf(a.z, w2v, fmaf(a.w, w3v, acc[k]))));
        }
    }

    // hop-2 attention weights (from r0) + fold tanh in-register
    float sc0[KN];
    float m = -1e30f;
    {
        const int4* r0p = (const int4*)(adj_rela + (size_t)n0 * KN);
        #pragma unroll
        for (int q = 0; q < 4; ++q) {
            const int4 rr = r0p[q];
            sc0[4*q+0] = costab[rr.x * NREL + rel];
            sc0[4*q+1] = costab[rr.y * NREL + rel];
            sc0[4*q+2] = costab[rr.z * NREL + rel];
            sc0[4*q+3] = costab[rr.w * NREL + rel];
        }
    }
    #pragma unroll
    for (int k = 0; k < KN; ++k) m = fmaxf(m, sc0[k]);
    float sum = 0.f;
    #pragma unroll
    for (int k = 0; k < KN; ++k) { sc0[k] = __expf(sc0[k] - m); sum += sc0[k]; }
    const float inv = __fdividef(1.f, sum);
    float fin = 0.f;
    #pragma unroll
    for (int k = 0; k < KN; ++k) fin = fmaf(sc0[k] * inv, fast_tanh(acc[k]), fin);
    s_fin[bl][e] = fin;
    __syncthreads();

    // out = tanh(fin @ W1 + b1)
    float o = b1[e];
    for (int ee4 = 0; ee4 < EMB / 4; ++ee4) {
        const float w0v = W1[(4 * ee4 + 0) * EMB + e];
        const float w1v = W1[(4 * ee4 + 1) * EMB + e];
        const float w2v = W1[(4 * ee4 + 2) * EMB + e];
        const float w3v = W1[(4 * ee4 + 3) * EMB + e];
        const float4 f = *(const float4*)&s_fin[bl][4 * ee4];
        o = fmaf(f.x, w0v, fmaf(f.y, w1v, fmaf(f.z, w2v, fmaf(f.w, w3v, o))));
    }
    out[(size_t)b * EMB + e] = fast_tanh(o);
}

// ---------------- Fallback fused kernel (round-3 verified correct) ----------
__global__ __launch_bounds__(1024) void pgra_fused(
    const int* __restrict__ node, const int* __restrict__ relation,
    const int* __restrict__ adj_node, const int* __restrict__ adj_rela,
    const float* __restrict__ node_table, const float* __restrict__ proj_table,
    const float* __restrict__ W0, const float* __restrict__ b0,
    const float* __restrict__ W1, const float* __restrict__ b1,
    const float* __restrict__ costab, float* __restrict__ out)
{
    const int b    = blockIdx.x;
    const int tid  = threadIdx.x;
    const int wave = tid >> 6;
    const int lane = tid & 63;

    __shared__ float s_agg[KN][EMB];
    __shared__ float s_part[2][EMB];
    __shared__ float s_fin[EMB];

    const int n0  = node[b];
    const int rel = relation[b];

    {
        const int j  = wave;
        const int n1 = adj_node[n0 * KN + j];
        const int4* n2p = (const int4*)(adj_node + (size_t)n1 * KN);
        const int4* r1p = (const int4*)(adj_rela + (size_t)n1 * KN);
        int   n2[KN];
        float sc[KN];
        #pragma unroll
        for (int q = 0; q < 4; ++q) {
            const int4 nn = n2p[q];
            const int4 rr = r1p[q];
            n2[4*q+0] = nn.x; n2[4*q+1] = nn.y; n2[4*q+2] = nn.z; n2[4*q+3] = nn.w;
            sc[4*q+0] = costab[rr.x * NREL + rel];
            sc[4*q+1] = costab[rr.y * NREL + rel];
            sc[4*q+2] = costab[rr.z * NREL + rel];
            sc[4*q+3] = costab[rr.w * NREL + rel];
        }
        float m = sc[0];
        #pragma unroll
        for (int k = 1; k < KN; ++k) m = fmaxf(m, sc[k]);
        float sum = 0.f;
        #pragma unroll
        for (int k = 0; k < KN; ++k) { sc[k] = __expf(sc[k] - m); sum += sc[k]; }
        const float inv = 1.f / sum;
        float ax = 0.f, ay = 0.f;
        #pragma unroll
        for (int k = 0; k < KN; ++k) {
            const float2 v = ((const float2*)(node_table + (size_t)n2[k] * EMB))[lane];
            ax = fmaf(sc[k], v.x, ax);
            ay = fmaf(sc[k], v.y, ay);
        }
        const float2 pj = ((const float2*)(proj_table + (size_t)rel * EMB))[lane];
        s_agg[j][2*lane]   = ax * inv * pj.x;
        s_agg[j][2*lane+1] = ay * inv * pj.y;
    }
    __syncthreads();

    if (tid < 256) {
        const int e  = tid & 127;
        const int g  = tid >> 7;
        const int jg = g * 8;
        float acc[8];
        const float bias = b0[e];
        #pragma unroll
        for (int q = 0; q < 8; ++q) acc[q] = bias;
        for (int ee4 = 0; ee4 < EMB / 4; ++ee4) {
            const float w0v = W0[(4 * ee4 + 0) * EMB + e];
            const float w1v = W0[(4 * ee4 + 1) * EMB + e];
            const float w2v = W0[(4 * ee4 + 2) * EMB + e];
            const float w3v = W0[(4 * ee4 + 3) * EMB + e];
            #pragma unroll
            for (int q = 0; q < 8; ++q) {
                const float4 a = *(const float4*)&s_agg[jg + q][4 * ee4];
                acc[q] = fmaf(a.x, w0v, fmaf(a.y, w1v, fmaf(a.z, w2v, fmaf(a.w, w3v, acc[q]))));
            }
        }
        float sc0[KN];
        float m = -1e30f;
        #pragma unroll
        for (int k = 0; k < KN; ++k) {
            sc0[k] = costab[adj_rela[n0 * KN + k] * NREL + rel];
            m = fmaxf(m, sc0[k]);
        }
        float sum = 0.f;
        #pragma unroll
        for (int k = 0; k < KN; ++k) { sc0[k] = __expf(sc0[k] - m); sum += sc0[k]; }
        const float inv = 1.f / sum;
        float part = 0.f;
        #pragma unroll
        for (int q = 0; q < 8; ++q)
            part = fmaf(sc0[jg + q] * inv, fast_tanh(acc[q]), part);
        s_part[g][e] = part;
    }
    __syncthreads();

    if (tid < EMB) s_fin[tid] = s_part[0][tid] + s_part[1][tid];
    __syncthreads();

    if (tid < EMB) {
        float acc = b1[tid];
        for (int ee = 0; ee < EMB; ++ee) acc = fmaf(s_fin[ee], W1[ee * EMB + tid], acc);
        out[(size_t)b * EMB + tid] = fast_tanh(acc);
    }
}

extern "C" void kernel_launch(void* const* d_in, const int* in_sizes, int n_in,
                              void* d_out, int out_size, void* d_ws, size_t ws_size,
                              hipStream_t stream) {
    const int*   node       = (const int*)d_in[0];
    const int*   relation   = (const int*)d_in[1];
    const int*   adj_node   = (const int*)d_in[2];
    const int*   adj_rela   = (const int*)d_in[3];
    const float* node_table = (const float*)d_in[4];
    const float* rela_table = (const float*)d_in[5];
    const float* proj_table = (const float*)d_in[6];
    const float* W0         = (const float*)d_in[7];
    const float* b0         = (const float*)d_in[8];
    const float* W1         = (const float*)d_in[9];
    const float* b1         = (const float*)d_in[10];
    float* outp = (float*)d_out;
    const int B = in_sizes[0];

    float* costab = (float*)d_ws;                    // 1024 floats = 4 KB
    float* agg    = (float*)d_ws + 1024;             // B*16*128 floats
    const size_t need = (size_t)(1024 + (size_t)B * KN * EMB) * sizeof(float);

    hipLaunchKernelGGL(pgra_costab_k, dim3(NREL * NREL / 4), dim3(256), 0, stream,
                       rela_table, costab);

    if (ws_size >= need) {
        const int half = B * KN / 2;     // 16384 waves, 2 pairs each
        hipLaunchKernelGGL(pgra_gather2, dim3((half + 3) / 4), dim3(256), 0, stream,
                           node, relation, adj_node, adj_rela,
                           node_table, proj_table, costab, agg, half);
        hipLaunchKernelGGL(pgra_tail2, dim3(B / 2), dim3(256), 0, stream,
                           node, relation, adj_rela, agg,
                           W0, b0, W1, b1, costab, outp);
    } else {
        hipLaunchKernelGGL(pgra_fused, dim3(B), dim3(1024), 0, stream,
                           node, relation, adj_node, adj_rela,
                           node_table, proj_table, W0, b0, W1, b1, costab, outp);
    }
}